// Round 4
// baseline (585.894 us; speedup 1.0000x reference)
//
#include <hip/hip_runtime.h>
#include <hip/hip_bf16.h>
#include <stdint.h>

#define M_MOL 128
#define L_SEQ 256
#define H_DIM 768
#define NH_   12
#define HD_   64
#define N_TOT (M_MOL * L_SEQ)

typedef __attribute__((ext_vector_type(8))) short bf16x8;
typedef __attribute__((ext_vector_type(4))) float f32x4;
typedef __attribute__((ext_vector_type(8))) unsigned short u16x8;
typedef __hip_bfloat16 bf16;

__device__ __forceinline__ float bf2f(bf16 x){ return __bfloat162float(x); }
__device__ __forceinline__ bf16 f2bf(float x){ return __float2bfloat16(x); }
__device__ __forceinline__ float bfbits2f(unsigned short u){
    return __uint_as_float(((unsigned)u) << 16);
}
__device__ __forceinline__ unsigned pk2(float lo, float hi){
    bf16 a = f2bf(lo), b = f2bf(hi);
    unsigned short ua, ub;
    __builtin_memcpy(&ua, &a, 2);
    __builtin_memcpy(&ub, &b, 2);
    return (unsigned)ua | ((unsigned)ub << 16);
}

typedef const __attribute__((address_space(1))) unsigned int* as1_u32p;
typedef __attribute__((address_space(3))) unsigned int* as3_u32p;
__device__ __forceinline__ void async_ld16(const void* g, const void* l) {
    __builtin_amdgcn_global_load_lds((as1_u32p)(unsigned long long)g,
                                     (as3_u32p)(unsigned int)(unsigned long long)l,
                                     16, 0, 0);
}

#define MFMA16(a,b,c) __builtin_amdgcn_mfma_f32_16x16x32_bf16((a),(b),(c),0,0,0)

// one kernel converts atom_features (12288 blocks) + 4 weight mats (288 each)
__global__ __launch_bounds__(256)
void cvt_all(const float* __restrict__ af, const float* __restrict__ Wq,
             const float* __restrict__ Wk, const float* __restrict__ Wv,
             const float* __restrict__ Wo,
             bf16* __restrict__ afb, bf16* __restrict__ Wcat, bf16* __restrict__ Wobf)
{
    const int b = blockIdx.x;
    const float* src; bf16* dst; int local;
    if (b < 12288) { src = af; dst = afb; local = b; }
    else {
        int r = b - 12288;
        int mat = r / 288; local = r % 288;
        src = mat==0 ? Wq : mat==1 ? Wk : mat==2 ? Wv : Wo;
        dst = (mat < 3) ? (Wcat + (size_t)mat*589824) : Wobf;
    }
    const size_t off = ((size_t)local*256 + threadIdx.x)*8;
    float4 a = *(const float4*)(src + off);
    float4 c = *(const float4*)(src + off + 4);
    uint4 o = { pk2(a.x,a.y), pk2(a.z,a.w), pk2(c.x,c.y), pk2(c.z,c.w) };
    *(uint4*)(dst + off) = o;
}

// ---------------------------------------------------------------------------
// 256x256 tile, 8 waves (2x4), BK=128, 6 K-tiles.
// A: LDS double-buffered (2 x 64 KiB), involution-swizzled 16B slots within
//    256B rows (slot ^= row&7), staged via inverse-swizzled global source
//    (256B-coalesced), global_load_lds width-16.
// B: NEVER staged -- weights (3.4 MB) are XCD-L2 resident; fragments loaded
//    straight to registers per tile, kk-major so compiler emits counted
//    vmcnt waits; wr-pair waves read identical addresses (L1 dedup).
// LDS read traffic halves vs A+B staging -> LDS:MFMA ratio ~0.8:1.
// vmcnt: stageA(T+2) then vmcnt(8) retires exactly A(T+1); tail vmcnt(0) @T=4.
// ---------------------------------------------------------------------------
__device__ __forceinline__ void gemm256_core(
    const bf16* __restrict__ Ap, const bf16* __restrict__ Wp,
    int rowBase, int colBase, char* sm, f32x4 (&acc)[8][4])
{
    const int t = threadIdx.x;
    const int w = t >> 6, lane = t & 63, quad = lane >> 4, r16 = lane & 15;
    const int wr = w >> 2, wc = w & 3;

    // staging: dest chunk c = p*512 + t -> LDS row c>>4, slot c&15.
    // LDS[r][slot] holds global k-chunk (slot ^ (r&7)); sr&7 == (p*32+sr)&7.
    const int sr = w*4 + quad;                    // row within 32-row pass group
    const int gk = ((r16 ^ (sr & 7)) << 3);       // global k-chunk offset (elems)
    // ds_read: row = wr*128 + mi*16 + r16 (row&7 == r16&7), slot = kk*4+quad
    const int aswz  = r16 & 7;
    const int arowB = (wr*128 + r16) * 256;       // byte base (+= mi*4096)

    // B fragment row pointers (per lane), ni = 0..3
    const bf16* brow0 = Wp + (size_t)(colBase + wc*64 +  0 + r16)*768 + quad*8;
    const bf16* brow1 = Wp + (size_t)(colBase + wc*64 + 16 + r16)*768 + quad*8;
    const bf16* brow2 = Wp + (size_t)(colBase + wc*64 + 32 + r16)*768 + quad*8;
    const bf16* brow3 = Wp + (size_t)(colBase + wc*64 + 48 + r16)*768 + quad*8;

#pragma unroll
    for (int i = 0; i < 8; ++i)
#pragma unroll
        for (int j = 0; j < 4; ++j) acc[i][j] = (f32x4){0.f,0.f,0.f,0.f};

    auto stageA = [&](int T) {
        char* base = sm + (T&1)*65536 + w*1024;
        const bf16* g = Ap + (size_t)(rowBase + sr)*768 + T*128 + gk;
#pragma unroll
        for (int p = 0; p < 8; ++p)
            async_ld16(g + (size_t)p*32*768, base + p*8192);
    };

    stageA(0); stageA(1);
    asm volatile("s_waitcnt vmcnt(8)" ::: "memory");
    __builtin_amdgcn_s_barrier();

    for (int T = 0; T < 6; ++T) {
        const char* Bf = sm + (T&1)*65536;
        const int tOff = T*128;

        // B direct loads, kk-major (oldest = first needed)
        bf16x8 b[4][4];
#pragma unroll
        for (int kk = 0; kk < 4; ++kk) {
            b[kk][0] = *(const bf16x8*)(brow0 + tOff + kk*32);
            b[kk][1] = *(const bf16x8*)(brow1 + tOff + kk*32);
            b[kk][2] = *(const bf16x8*)(brow2 + tOff + kk*32);
            b[kk][3] = *(const bf16x8*)(brow3 + tOff + kk*32);
        }

#pragma unroll
        for (int kk = 0; kk < 4; ++kk) {
            bf16x8 a0[8];
#pragma unroll
            for (int mi = 0; mi < 8; ++mi)
                a0[mi] = *(const bf16x8*)(Bf + arowB + mi*4096 +
                                          (((kk*4 + quad) ^ aswz) << 4));
            __builtin_amdgcn_s_setprio(1);
#pragma unroll
            for (int mi = 0; mi < 8; ++mi)
#pragma unroll
                for (int ni = 0; ni < 4; ++ni)
                    acc[mi][ni] = MFMA16(a0[mi], b[kk][ni], acc[mi][ni]);
            __builtin_amdgcn_s_setprio(0);
        }

        asm volatile("s_waitcnt lgkmcnt(0)" ::: "memory");
        __builtin_amdgcn_sched_barrier(0);
        __builtin_amdgcn_s_barrier();              // all waves done reading buf

        if (T+2 < 6) {
            stageA(T+2);
            asm volatile("s_waitcnt vmcnt(8)" ::: "memory");  // A(T+1) retired
        } else if (T == 4) {
            asm volatile("s_waitcnt vmcnt(0)" ::: "memory");  // A(5) retired
        }
        if (T < 5) __builtin_amdgcn_s_barrier();
    }
}

// fused QKV GEMM: grid 1152 = 8 XCD x (16 rowBlk x 9 colBlk), col fastest
__global__ __launch_bounds__(512, 2)
void gemm_qkv(const bf16* __restrict__ A, const bf16* __restrict__ W,
              const float* __restrict__ bq, const float* __restrict__ bk,
              const float* __restrict__ bv,
              bf16* __restrict__ qb, bf16* __restrict__ kb, bf16* __restrict__ vb)
{
    __shared__ __align__(16) char sm[131072];
    const int bid = blockIdx.x;
    const int xcd = bid & 7, idx = bid >> 3;           // idx 0..143
    const int rowBlk = xcd*16 + idx/9;
    const int colBlk = idx - (idx/9)*9;
    const int rowBase = rowBlk * 256;
    const int colBase = colBlk * 256;

    f32x4 acc[8][4];
    gemm256_core(A, W, rowBase, colBase, sm, acc);

    const int t = threadIdx.x;
    const int w = t >> 6, lane = t & 63, quad = lane >> 4, r16 = lane & 15;
    const int wr = w >> 2, wc = w & 3;
    const int sel = colBlk / 3;                        // 0=q 1=k 2=v
    const float* bias = sel==0 ? bq : sel==1 ? bk : bv;
    bf16* C = sel==0 ? qb : sel==1 ? kb : vb;
    const int colSec = colBase - sel*768;
#pragma unroll
    for (int nj = 0; nj < 4; ++nj) {
        int col = colSec + wc*64 + nj*16 + r16;
        float bb = bias[col];
#pragma unroll
        for (int mi = 0; mi < 8; ++mi) {
            int row0 = rowBase + wr*128 + mi*16 + quad*4;
#pragma unroll
            for (int rr = 0; rr < 4; ++rr)
                C[(size_t)(row0+rr)*768 + col] = f2bf(acc[mi][nj][rr] + bb);
        }
    }
}

// Wo projection: grid 384 = 8 XCD x (16 rowBlk x 3 colBlk), col fastest
__global__ __launch_bounds__(512, 2)
void gemm_o(const bf16* __restrict__ A, const bf16* __restrict__ W,
            const float* __restrict__ bo, bf16* __restrict__ C)
{
    __shared__ __align__(16) char sm[131072];
    const int bid = blockIdx.x;
    const int xcd = bid & 7, idx = bid >> 3;           // idx 0..47
    const int rowBlk = xcd*16 + idx/3;
    const int colBlk = idx - (idx/3)*3;
    const int rowBase = rowBlk * 256;
    const int colBase = colBlk * 256;

    f32x4 acc[8][4];
    gemm256_core(A, W, rowBase, colBase, sm, acc);

    const int t = threadIdx.x;
    const int w = t >> 6, lane = t & 63, quad = lane >> 4, r16 = lane & 15;
    const int wr = w >> 2, wc = w & 3;
#pragma unroll
    for (int nj = 0; nj < 4; ++nj) {
        int col = colBase + wc*64 + nj*16 + r16;
        float bb = bo[col];
#pragma unroll
        for (int mi = 0; mi < 8; ++mi) {
            int row0 = rowBase + wr*128 + mi*16 + quad*4;
#pragma unroll
            for (int rr = 0; rr < 4; ++rr)
                C[(size_t)(row0+rr)*768 + col] = f2bf(acc[mi][nj][rr] + bb);
        }
    }
}

// one block per (m, nh); 256 threads = 4 waves; 4 passes of 64 q rows.
// K fragments hoisted into registers (loaded once, reused all 4 passes).
__global__ __launch_bounds__(256, 2)
void attn_kernel(const bf16* __restrict__ qbuf, const bf16* __restrict__ kbuf,
                 bf16* vctx, const int* __restrict__ a_sizes)
{
    __shared__ __align__(16) bf16 VT[64*264];
    __shared__ __align__(16) bf16 P[4*16*264];

    const int b = blockIdx.x;
    const int m = b / NH_, nh = b % NH_;
    const int t = threadIdx.x;
    const int w = t >> 6, lane = t & 63, quad = lane >> 4, r16 = lane & 15;
    const int size = a_sizes[m];
    const size_t headOff = (size_t)m*L_SEQ*768 + nh*64;

    {
        const int k0 = (t & 127) * 2;
        const int dh = (t >> 7) * 32;
        const bf16* v0 = vctx + headOff + (size_t)k0*768 + dh;
        const bf16* v1 = v0 + 768;
        u16x8 r0[4], r1[4];
#pragma unroll
        for (int c = 0; c < 4; ++c) {
            r0[c] = *(const u16x8*)(v0 + c*8);
            r1[c] = *(const u16x8*)(v1 + c*8);
        }
#pragma unroll
        for (int c = 0; c < 4; ++c)
#pragma unroll
            for (int j = 0; j < 8; ++j) {
                unsigned val = (unsigned)r0[c][j] | ((unsigned)r1[c][j] << 16);
                *(unsigned*)(&VT[(size_t)(dh + c*8 + j)*264 + k0]) = val;
            }
    }
    __syncthreads();

    // hoist K fragments: full head K-slice per wave, once
    bf16x8 kf0[16], kf1[16];
#pragma unroll
    for (int kt = 0; kt < 16; ++kt) {
        const bf16* krow = kbuf + headOff + (size_t)(kt*16 + r16)*768 + quad*8;
        kf0[kt] = *(const bf16x8*)(krow);
        kf1[kt] = *(const bf16x8*)(krow + 32);
    }

    bf16* Pw = P + w*16*264;
    for (int pass = 0; pass < 4; ++pass) {
        const int qrow0 = pass*64 + w*16;
        bf16x8 aq0, aq1;
        {
            const bf16* qrow = qbuf + headOff + (size_t)(qrow0 + r16)*768 + quad*8;
            aq0 = *(const bf16x8*)(qrow);
            aq1 = *(const bf16x8*)(qrow + 32);
        }
        f32x4 S[16];
#pragma unroll
        for (int kt = 0; kt < 16; ++kt) {
            f32x4 s = (f32x4){0.f,0.f,0.f,0.f};
            s = __builtin_amdgcn_mfma_f32_16x16x32_bf16(aq0, kf0[kt], s, 0, 0, 0);
            s = __builtin_amdgcn_mfma_f32_16x16x32_bf16(aq1, kf1[kt], s, 0, 0, 0);
            S[kt] = s;
        }
        float mrow[4] = {-1e30f,-1e30f,-1e30f,-1e30f};
#pragma unroll
        for (int kt = 0; kt < 16; ++kt) {
            int key = kt*16 + r16;
#pragma unroll
            for (int rr = 0; rr < 4; ++rr) {
                float s = S[kt][rr] * 0.125f;
                if (key >= size) s = -1e9f;
                S[kt][rr] = s;
                mrow[rr] = fmaxf(mrow[rr], s);
            }
        }
#pragma unroll
        for (int msk = 1; msk < 16; msk <<= 1)
#pragma unroll
            for (int rr = 0; rr < 4; ++rr)
                mrow[rr] = fmaxf(mrow[rr], __shfl_xor(mrow[rr], msk));
        float lrow[4] = {0.f,0.f,0.f,0.f};
#pragma unroll
        for (int kt = 0; kt < 16; ++kt) {
#pragma unroll
            for (int rr = 0; rr < 4; ++rr) {
                float p = __expf(S[kt][rr] - mrow[rr]);
                lrow[rr] += p;
                Pw[(quad*4+rr)*264 + kt*16 + r16] = f2bf(p);
            }
        }
#pragma unroll
        for (int msk = 1; msk < 16; msk <<= 1)
#pragma unroll
            for (int rr = 0; rr < 4; ++rr)
                lrow[rr] += __shfl_xor(lrow[rr], msk);
        asm volatile("s_waitcnt lgkmcnt(0)" ::: "memory");

        bf16x8 pa[8];
#pragma unroll
        for (int kb2 = 0; kb2 < 8; ++kb2)
            pa[kb2] = *(const bf16x8*)(&Pw[r16*264 + kb2*32 + quad*8]);
        float inv[4];
#pragma unroll
        for (int rr = 0; rr < 4; ++rr) inv[rr] = 1.f / lrow[rr];
#pragma unroll
        for (int dt = 0; dt < 4; ++dt) {
            f32x4 c = (f32x4){0.f,0.f,0.f,0.f};
#pragma unroll
            for (int kb2 = 0; kb2 < 8; ++kb2) {
                bf16x8 vb8 = *(const bf16x8*)(&VT[(dt*16 + r16)*264 + kb2*32 + quad*8]);
                c = __builtin_amdgcn_mfma_f32_16x16x32_bf16(pa[kb2], vb8, c, 0, 0, 0);
            }
#pragma unroll
            for (int rr = 0; rr < 4; ++rr) {
                int q = qrow0 + quad*4 + rr;
                vctx[headOff + (size_t)q*768 + dt*16 + r16] = f2bf(c[rr] * inv[rr]);
            }
        }
    }
}

__global__ __launch_bounds__(256, 4)
void ln_kernel(const bf16* __restrict__ proj, const float* __restrict__ af,
               const float* __restrict__ gamma, const float* __restrict__ beta,
               const int* __restrict__ a_sizes, float* __restrict__ out)
{
    const int w = threadIdx.x >> 6, lane = threadIdx.x & 63;
    const int n = blockIdx.x * 4 + w;
    const int m = n >> 8, l = n & 255;
    const int size = a_sizes[m];
    float* orow = out + (size_t)n * 768;
    if (l >= size) {
        float4 z = {0.f,0.f,0.f,0.f};
#pragma unroll
        for (int i = 0; i < 3; ++i) *(float4*)(&orow[i*256 + lane*4]) = z;
        return;
    }
    const bf16*  prow = proj + (size_t)n * 768;
    const float* xrow = af   + (size_t)n * 768;
    float y[3][4];
    float s = 0.f;
#pragma unroll
    for (int i = 0; i < 3; ++i) {
        int c = i*256 + lane*4;
        float4 xv = *(const float4*)(&xrow[c]);
        ushort4 pv = *(const ushort4*)(&prow[c]);
        y[i][0] = xv.x + bfbits2f(pv.x);
        y[i][1] = xv.y + bfbits2f(pv.y);
        y[i][2] = xv.z + bfbits2f(pv.z);
        y[i][3] = xv.w + bfbits2f(pv.w);
        s += y[i][0] + y[i][1] + y[i][2] + y[i][3];
    }
#pragma unroll
    for (int msk = 1; msk < 64; msk <<= 1) s += __shfl_xor(s, msk);
    float mu = s * (1.f/768.f);
    float v = 0.f;
#pragma unroll
    for (int i = 0; i < 3; ++i)
#pragma unroll
        for (int j = 0; j < 4; ++j) { float d = y[i][j] - mu; v += d*d; }
#pragma unroll
    for (int msk = 1; msk < 64; msk <<= 1) v += __shfl_xor(v, msk);
    float rstd = rsqrtf(v * (1.f/768.f) + 1e-5f);
#pragma unroll
    for (int i = 0; i < 3; ++i) {
        int c = i*256 + lane*4;
        float4 gv = *(const float4*)(&gamma[c]);
        float4 bv = *(const float4*)(&beta[c]);
        float4 o;
        o.x = (y[i][0] - mu) * rstd * gv.x + bv.x;
        o.y = (y[i][1] - mu) * rstd * gv.y + bv.y;
        o.z = (y[i][2] - mu) * rstd * gv.z + bv.z;
        o.w = (y[i][3] - mu) * rstd * gv.w + bv.w;
        *(float4*)(&orow[c]) = o;
    }
}

extern "C" void kernel_launch(void* const* d_in, const int* in_sizes, int n_in,
                              void* d_out, int out_size, void* d_ws, size_t ws_size,
                              hipStream_t stream)
{
    (void)in_sizes; (void)n_in; (void)out_size; (void)ws_size;
    const float* af    = (const float*)d_in[0];
    const float* Wq    = (const float*)d_in[1];
    const float* bq    = (const float*)d_in[2];
    const float* Wk    = (const float*)d_in[3];
    const float* bk    = (const float*)d_in[4];
    const float* Wv    = (const float*)d_in[5];
    const float* bv    = (const float*)d_in[6];
    const float* Wo    = (const float*)d_in[7];
    const float* bo    = (const float*)d_in[8];
    const float* gamma = (const float*)d_in[9];
    const float* beta  = (const float*)d_in[10];
    const int* a_sizes = (const int*)d_in[12];
    float* outp = (float*)d_out;

    // d_ws: qb, kb, vb (bf16 N x 768 each = 144 MiB; proven ws >= 192 MiB)
    bf16* qb = (bf16*)d_ws;
    bf16* kb = qb + (size_t)N_TOT * 768;
    bf16* vb = kb + (size_t)N_TOT * 768;          // ctx overwrites in place
    // d_out doubles as scratch until ln_kernel overwrites it (stream-ordered):
    // afb 50.3 MB + Wcat 3.4 MB + Wobf 1.1 MB < 100.6 MB output buffer
    bf16* afb  = (bf16*)d_out;
    bf16* Wcat = afb + (size_t)N_TOT * 768;
    bf16* Wobf = Wcat + (size_t)2304 * 768;

    cvt_all<<<dim3(12288 + 4*288), 256, 0, stream>>>(af, Wq, Wk, Wv, Wo, afb, Wcat, Wobf);
    gemm_qkv<<<dim3(1152), 512, 0, stream>>>(afb, Wcat, bq, bk, bv, qb, kb, vb);
    attn_kernel<<<dim3(M_MOL * NH_), 256, 0, stream>>>(qb, kb, vb, a_sizes);
    gemm_o<<<dim3(384), 512, 0, stream>>>(vb, Wobf, bo, qb);
    ln_kernel<<<dim3(N_TOT / 4), 256, 0, stream>>>(qb, af, gamma, beta, a_sizes, outp);
}

// Round 6
// 489.627 us; speedup vs baseline: 1.1966x; 1.1966x over previous
//
#include <hip/hip_runtime.h>
#include <hip/hip_bf16.h>
#include <stdint.h>

#define M_MOL 128
#define L_SEQ 256
#define H_DIM 768
#define NH_   12
#define HD_   64
#define N_TOT (M_MOL * L_SEQ)

typedef __attribute__((ext_vector_type(8))) short bf16x8;
typedef __attribute__((ext_vector_type(4))) float f32x4;
typedef __attribute__((ext_vector_type(8))) unsigned short u16x8;
typedef __hip_bfloat16 bf16;

__device__ __forceinline__ float bf2f(bf16 x){ return __bfloat162float(x); }
__device__ __forceinline__ bf16 f2bf(float x){ return __float2bfloat16(x); }
__device__ __forceinline__ float bfbits2f(unsigned short u){
    return __uint_as_float(((unsigned)u) << 16);
}
__device__ __forceinline__ unsigned pk2(float lo, float hi){
    bf16 a = f2bf(lo), b = f2bf(hi);
    unsigned short ua, ub;
    __builtin_memcpy(&ua, &a, 2);
    __builtin_memcpy(&ub, &b, 2);
    return (unsigned)ua | ((unsigned)ub << 16);
}

typedef const __attribute__((address_space(1))) unsigned int* as1_u32p;
typedef __attribute__((address_space(3))) unsigned int* as3_u32p;
__device__ __forceinline__ void async_ld16(const void* g, const void* l) {
    __builtin_amdgcn_global_load_lds((as1_u32p)(unsigned long long)g,
                                     (as3_u32p)(unsigned int)(unsigned long long)l,
                                     16, 0, 0);
}

#define MFMA16(a,b,c) __builtin_amdgcn_mfma_f32_16x16x32_bf16((a),(b),(c),0,0,0)

// one kernel converts atom_features (12288 blocks) + 4 weight mats (288 each)
__global__ __launch_bounds__(256)
void cvt_all(const float* __restrict__ af, const float* __restrict__ Wq,
             const float* __restrict__ Wk, const float* __restrict__ Wv,
             const float* __restrict__ Wo,
             bf16* __restrict__ afb, bf16* __restrict__ Wcat, bf16* __restrict__ Wobf)
{
    const int b = blockIdx.x;
    const float* src; bf16* dst; int local;
    if (b < 12288) { src = af; dst = afb; local = b; }
    else {
        int r = b - 12288;
        int mat = r / 288; local = r % 288;
        src = mat==0 ? Wq : mat==1 ? Wk : mat==2 ? Wv : Wo;
        dst = (mat < 3) ? (Wcat + (size_t)mat*589824) : Wobf;
    }
    const size_t off = ((size_t)local*256 + threadIdx.x)*8;
    float4 a = *(const float4*)(src + off);
    float4 c = *(const float4*)(src + off + 4);
    uint4 o = { pk2(a.x,a.y), pk2(a.z,a.w), pk2(c.x,c.y), pk2(c.z,c.w) };
    *(uint4*)(dst + off) = o;
}

// ---------------------------------------------------------------------------
// 256x256 tile, BK=64, 8-wave, SINGLE-barrier-per-tile pipelined core.
// Round-3 structure (proven: 0 bank conflicts, 149us) minus the mid-barrier:
// both A and B are staged ONE tile ahead into the OTHER buffer, so there is
// no same-buffer write hazard -> one barrier per K-tile (12 total).
//   - stage(T+1) targets buffer (T+1)&1, last read in tile T-1; its readers
//     drained lgkmcnt(0) before barrier(T-1), which the staging wave passed.
//   - vmcnt(0) at tile end is issued a full tile (~1500-2000cy) after the
//     loads -> HBM latency fully hidden, drain is ~free.
// LDS: 2 x (A 256x64 + B 256x64) bf16 = 128 KiB, involution-swizzled 16B
// slots within 128B rows (slot ^= row&7), staged via inverse-swizzled global
// source, global_load_lds width-16.
// ---------------------------------------------------------------------------
__device__ __forceinline__ void gemm256_core(
    const bf16* __restrict__ Ap, const bf16* __restrict__ Wp,
    int rowBase, int colBase, char* sm, f32x4 (&acc)[8][4])
{
    const int t = threadIdx.x;
    const int w = t >> 6, lane = t & 63, quad = lane >> 4, r16 = lane & 15;
    const int wr = w >> 2, wc = w & 3;
    // staging decomposition: thread t stages rows r0 and r0+64 of a 128-row half
    const int r0  = t >> 3;
    const int kbe = (((t & 7) ^ (r0 & 7)) << 3);   // pre-swizzled source col (elems)
    // ds_read bases (byte offsets inside a buffer)
    const int aBase = (wr*128 + r16) * 128;
    const int bBase = 32768 + (wc*64 + r16) * 128;
    const int swz = (r16 & 7) << 4;
    const int cs0 = (0  + quad*16) ^ swz;          // k-step 0
    const int cs1 = (64 + quad*16) ^ swz;          // k-step 1

#pragma unroll
    for (int i = 0; i < 8; ++i)
#pragma unroll
        for (int j = 0; j < 4; ++j) acc[i][j] = (f32x4){0.f,0.f,0.f,0.f};

    // stage one 128-row half-tile (16 KiB) of A (isB=0) or B (isB=1) for K-tile T
    auto stage = [&](int isB, int T, int h) {
        const bf16* g = isB ? Wp : Ap;
        const int gr0 = (isB ? colBase : rowBase) + h*128 + r0;
        const bf16* p0 = g + (size_t)gr0*768 + T*64 + kbe;
        char* reg = sm + ((T&1)*65536 + isB*32768 + h*16384 + w*1024);
        async_ld16(p0, reg);
        async_ld16(p0 + (size_t)64*768, reg + 8192);
    };
    auto stageTile = [&](int T) {
        stage(0,T,0); stage(0,T,1); stage(1,T,0); stage(1,T,1);
    };

    // prologue: tile 0 fully staged and drained
    stageTile(0);
    asm volatile("s_waitcnt vmcnt(0)" ::: "memory");
    __builtin_amdgcn_s_barrier();

    bf16x8 a0[4][2], a1[4][2], b0v[2][2], b1v[2][2];

    for (int T = 0; T < 12; ++T) {
        const char* Bf = sm + (T&1)*65536;

        // prefetch next tile into the other buffer (no same-buffer hazard)
        if (T+1 < 12) stageTile(T+1);

        // fragment reads + 4 MFMA quadrant clusters; compiler interleaves
        // with counted lgkmcnt so reads overlap the early clusters
#pragma unroll
        for (int mi = 0; mi < 4; ++mi) {
            a0[mi][0] = *(const bf16x8*)(Bf + aBase + mi*2048 + cs0);
            a0[mi][1] = *(const bf16x8*)(Bf + aBase + mi*2048 + cs1);
        }
#pragma unroll
        for (int ni = 0; ni < 2; ++ni) {
            b0v[ni][0] = *(const bf16x8*)(Bf + bBase + ni*2048 + cs0);
            b0v[ni][1] = *(const bf16x8*)(Bf + bBase + ni*2048 + cs1);
        }
        __builtin_amdgcn_s_setprio(1);
#pragma unroll
        for (int mi = 0; mi < 4; ++mi)
#pragma unroll
            for (int ni = 0; ni < 2; ++ni) {
                acc[mi][ni] = MFMA16(a0[mi][0], b0v[ni][0], acc[mi][ni]);
                acc[mi][ni] = MFMA16(a0[mi][1], b0v[ni][1], acc[mi][ni]);
            }
        __builtin_amdgcn_s_setprio(0);
#pragma unroll
        for (int mi = 0; mi < 4; ++mi) {
            a1[mi][0] = *(const bf16x8*)(Bf + aBase + 8192 + mi*2048 + cs0);
            a1[mi][1] = *(const bf16x8*)(Bf + aBase + 8192 + mi*2048 + cs1);
        }
        __builtin_amdgcn_s_setprio(1);
#pragma unroll
        for (int mi = 0; mi < 4; ++mi)
#pragma unroll
            for (int ni = 0; ni < 2; ++ni) {
                acc[4+mi][ni] = MFMA16(a1[mi][0], b0v[ni][0], acc[4+mi][ni]);
                acc[4+mi][ni] = MFMA16(a1[mi][1], b0v[ni][1], acc[4+mi][ni]);
            }
        __builtin_amdgcn_s_setprio(0);
#pragma unroll
        for (int ni = 0; ni < 2; ++ni) {
            b1v[ni][0] = *(const bf16x8*)(Bf + bBase + 4096 + ni*2048 + cs0);
            b1v[ni][1] = *(const bf16x8*)(Bf + bBase + 4096 + ni*2048 + cs1);
        }
        __builtin_amdgcn_s_setprio(1);
#pragma unroll
        for (int mi = 0; mi < 4; ++mi)
#pragma unroll
            for (int ni = 0; ni < 2; ++ni) {
                acc[mi][2+ni] = MFMA16(a0[mi][0], b1v[ni][0], acc[mi][2+ni]);
                acc[mi][2+ni] = MFMA16(a0[mi][1], b1v[ni][1], acc[mi][2+ni]);
            }
#pragma unroll
        for (int mi = 0; mi < 4; ++mi)
#pragma unroll
            for (int ni = 0; ni < 2; ++ni) {
                acc[4+mi][2+ni] = MFMA16(a1[mi][0], b1v[ni][0], acc[4+mi][2+ni]);
                acc[4+mi][2+ni] = MFMA16(a1[mi][1], b1v[ni][1], acc[4+mi][2+ni]);
            }
        __builtin_amdgcn_s_setprio(0);

        // all current-buffer reads done; next tile's loads landed
        asm volatile("s_waitcnt lgkmcnt(0)" ::: "memory");
        __builtin_amdgcn_sched_barrier(0);
        if (T+1 < 12) { asm volatile("s_waitcnt vmcnt(0)" ::: "memory"); }
        if (T < 11)   __builtin_amdgcn_s_barrier();
    }
}

// fused QKV GEMM: grid 1152 = 8 XCD x (16 rowBlk x 9 colBlk), col fastest
__global__ __launch_bounds__(512, 2)
void gemm_qkv(const bf16* __restrict__ A, const bf16* __restrict__ W,
              const float* __restrict__ bq, const float* __restrict__ bk,
              const float* __restrict__ bv,
              bf16* __restrict__ qb, bf16* __restrict__ kb, bf16* __restrict__ vb)
{
    __shared__ __align__(16) char sm[131072];
    const int bid = blockIdx.x;
    const int xcd = bid & 7, idx = bid >> 3;           // idx 0..143
    const int rowBlk = xcd*16 + idx/9;
    const int colBlk = idx - (idx/9)*9;
    const int rowBase = rowBlk * 256;
    const int colBase = colBlk * 256;

    f32x4 acc[8][4];
    gemm256_core(A, W, rowBase, colBase, sm, acc);

    const int t = threadIdx.x;
    const int w = t >> 6, lane = t & 63, quad = lane >> 4, r16 = lane & 15;
    const int wr = w >> 2, wc = w & 3;
    const int sel = colBlk / 3;                        // 0=q 1=k 2=v
    const float* bias = sel==0 ? bq : sel==1 ? bk : bv;
    bf16* C = sel==0 ? qb : sel==1 ? kb : vb;
    const int colSec = colBase - sel*768;
#pragma unroll
    for (int nj = 0; nj < 4; ++nj) {
        int col = colSec + wc*64 + nj*16 + r16;
        float bb = bias[col];
#pragma unroll
        for (int mi = 0; mi < 8; ++mi) {
            int row0 = rowBase + wr*128 + mi*16 + quad*4;
#pragma unroll
            for (int rr = 0; rr < 4; ++rr)
                C[(size_t)(row0+rr)*768 + col] = f2bf(acc[mi][nj][rr] + bb);
        }
    }
}

// Wo projection: grid 384 = 8 XCD x (16 rowBlk x 3 colBlk), col fastest
__global__ __launch_bounds__(512, 2)
void gemm_o(const bf16* __restrict__ A, const bf16* __restrict__ W,
            const float* __restrict__ bo, bf16* __restrict__ C)
{
    __shared__ __align__(16) char sm[131072];
    const int bid = blockIdx.x;
    const int xcd = bid & 7, idx = bid >> 3;           // idx 0..47
    const int rowBlk = xcd*16 + idx/3;
    const int colBlk = idx - (idx/3)*3;
    const int rowBase = rowBlk * 256;
    const int colBase = colBlk * 256;

    f32x4 acc[8][4];
    gemm256_core(A, W, rowBase, colBase, sm, acc);

    const int t = threadIdx.x;
    const int w = t >> 6, lane = t & 63, quad = lane >> 4, r16 = lane & 15;
    const int wr = w >> 2, wc = w & 3;
#pragma unroll
    for (int nj = 0; nj < 4; ++nj) {
        int col = colBase + wc*64 + nj*16 + r16;
        float bb = bo[col];
#pragma unroll
        for (int mi = 0; mi < 8; ++mi) {
            int row0 = rowBase + wr*128 + mi*16 + quad*4;
#pragma unroll
            for (int rr = 0; rr < 4; ++rr)
                C[(size_t)(row0+rr)*768 + col] = f2bf(acc[mi][nj][rr] + bb);
        }
    }
}

// one block per (m, nh); 256 threads = 4 waves; 4 passes of 64 q rows.
// K fragments hoisted into registers (loaded once, reused all 4 passes).
__global__ __launch_bounds__(256, 2)
void attn_kernel(const bf16* __restrict__ qbuf, const bf16* __restrict__ kbuf,
                 bf16* vctx, const int* __restrict__ a_sizes)
{
    __shared__ __align__(16) bf16 VT[64*264];
    __shared__ __align__(16) bf16 P[4*16*264];

    const int b = blockIdx.x;
    const int m = b / NH_, nh = b % NH_;
    const int t = threadIdx.x;
    const int w = t >> 6, lane = t & 63, quad = lane >> 4, r16 = lane & 15;
    const int size = a_sizes[m];
    const size_t headOff = (size_t)m*L_SEQ*768 + nh*64;

    {
        const int k0 = (t & 127) * 2;
        const int dh = (t >> 7) * 32;
        const bf16* v0 = vctx + headOff + (size_t)k0*768 + dh;
        const bf16* v1 = v0 + 768;
        u16x8 r0[4], r1[4];
#pragma unroll
        for (int c = 0; c < 4; ++c) {
            r0[c] = *(const u16x8*)(v0 + c*8);
            r1[c] = *(const u16x8*)(v1 + c*8);
        }
#pragma unroll
        for (int c = 0; c < 4; ++c)
#pragma unroll
            for (int j = 0; j < 8; ++j) {
                unsigned val = (unsigned)r0[c][j] | ((unsigned)r1[c][j] << 16);
                *(unsigned*)(&VT[(size_t)(dh + c*8 + j)*264 + k0]) = val;
            }
    }
    __syncthreads();

    // hoist K fragments: full head K-slice per wave, once
    bf16x8 kf0[16], kf1[16];
#pragma unroll
    for (int kt = 0; kt < 16; ++kt) {
        const bf16* krow = kbuf + headOff + (size_t)(kt*16 + r16)*768 + quad*8;
        kf0[kt] = *(const bf16x8*)(krow);
        kf1[kt] = *(const bf16x8*)(krow + 32);
    }

    bf16* Pw = P + w*16*264;
    for (int pass = 0; pass < 4; ++pass) {
        const int qrow0 = pass*64 + w*16;
        bf16x8 aq0, aq1;
        {
            const bf16* qrow = qbuf + headOff + (size_t)(qrow0 + r16)*768 + quad*8;
            aq0 = *(const bf16x8*)(qrow);
            aq1 = *(const bf16x8*)(qrow + 32);
        }
        f32x4 S[16];
#pragma unroll
        for (int kt = 0; kt < 16; ++kt) {
            f32x4 s = (f32x4){0.f,0.f,0.f,0.f};
            s = __builtin_amdgcn_mfma_f32_16x16x32_bf16(aq0, kf0[kt], s, 0, 0, 0);
            s = __builtin_amdgcn_mfma_f32_16x16x32_bf16(aq1, kf1[kt], s, 0, 0, 0);
            S[kt] = s;
        }
        float mrow[4] = {-1e30f,-1e30f,-1e30f,-1e30f};
#pragma unroll
        for (int kt = 0; kt < 16; ++kt) {
            int key = kt*16 + r16;
#pragma unroll
            for (int rr = 0; rr < 4; ++rr) {
                float s = S[kt][rr] * 0.125f;
                if (key >= size) s = -1e9f;
                S[kt][rr] = s;
                mrow[rr] = fmaxf(mrow[rr], s);
            }
        }
#pragma unroll
        for (int msk = 1; msk < 16; msk <<= 1)
#pragma unroll
            for (int rr = 0; rr < 4; ++rr)
                mrow[rr] = fmaxf(mrow[rr], __shfl_xor(mrow[rr], msk));
        float lrow[4] = {0.f,0.f,0.f,0.f};
#pragma unroll
        for (int kt = 0; kt < 16; ++kt) {
#pragma unroll
            for (int rr = 0; rr < 4; ++rr) {
                float p = __expf(S[kt][rr] - mrow[rr]);
                lrow[rr] += p;
                Pw[(quad*4+rr)*264 + kt*16 + r16] = f2bf(p);
            }
        }
#pragma unroll
        for (int msk = 1; msk < 16; msk <<= 1)
#pragma unroll
            for (int rr = 0; rr < 4; ++rr)
                lrow[rr] += __shfl_xor(lrow[rr], msk);
        asm volatile("s_waitcnt lgkmcnt(0)" ::: "memory");

        bf16x8 pa[8];
#pragma unroll
        for (int kb2 = 0; kb2 < 8; ++kb2)
            pa[kb2] = *(const bf16x8*)(&Pw[r16*264 + kb2*32 + quad*8]);
        float inv[4];
#pragma unroll
        for (int rr = 0; rr < 4; ++rr) inv[rr] = 1.f / lrow[rr];
#pragma unroll
        for (int dt = 0; dt < 4; ++dt) {
            f32x4 c = (f32x4){0.f,0.f,0.f,0.f};
#pragma unroll
            for (int kb2 = 0; kb2 < 8; ++kb2) {
                bf16x8 vb8 = *(const bf16x8*)(&VT[(dt*16 + r16)*264 + kb2*32 + quad*8]);
                c = __builtin_amdgcn_mfma_f32_16x16x32_bf16(pa[kb2], vb8, c, 0, 0, 0);
            }
#pragma unroll
            for (int rr = 0; rr < 4; ++rr) {
                int q = qrow0 + quad*4 + rr;
                vctx[headOff + (size_t)q*768 + dt*16 + r16] = f2bf(c[rr] * inv[rr]);
            }
        }
    }
}

__global__ __launch_bounds__(256, 4)
void ln_kernel(const bf16* __restrict__ proj, const float* __restrict__ af,
               const float* __restrict__ gamma, const float* __restrict__ beta,
               const int* __restrict__ a_sizes, float* __restrict__ out)
{
    const int w = threadIdx.x >> 6, lane = threadIdx.x & 63;
    const int n = blockIdx.x * 4 + w;
    const int m = n >> 8, l = n & 255;
    const int size = a_sizes[m];
    float* orow = out + (size_t)n * 768;
    if (l >= size) {
        float4 z = {0.f,0.f,0.f,0.f};
#pragma unroll
        for (int i = 0; i < 3; ++i) *(float4*)(&orow[i*256 + lane*4]) = z;
        return;
    }
    const bf16*  prow = proj + (size_t)n * 768;
    const float* xrow = af   + (size_t)n * 768;
    float y[3][4];
    float s = 0.f;
#pragma unroll
    for (int i = 0; i < 3; ++i) {
        int c = i*256 + lane*4;
        float4 xv = *(const float4*)(&xrow[c]);
        ushort4 pv = *(const ushort4*)(&prow[c]);
        y[i][0] = xv.x + bfbits2f(pv.x);
        y[i][1] = xv.y + bfbits2f(pv.y);
        y[i][2] = xv.z + bfbits2f(pv.z);
        y[i][3] = xv.w + bfbits2f(pv.w);
        s += y[i][0] + y[i][1] + y[i][2] + y[i][3];
    }
#pragma unroll
    for (int msk = 1; msk < 64; msk <<= 1) s += __shfl_xor(s, msk);
    float mu = s * (1.f/768.f);
    float v = 0.f;
#pragma unroll
    for (int i = 0; i < 3; ++i)
#pragma unroll
        for (int j = 0; j < 4; ++j) { float d = y[i][j] - mu; v += d*d; }
#pragma unroll
    for (int msk = 1; msk < 64; msk <<= 1) v += __shfl_xor(v, msk);
    float rstd = rsqrtf(v * (1.f/768.f) + 1e-5f);
#pragma unroll
    for (int i = 0; i < 3; ++i) {
        int c = i*256 + lane*4;
        float4 gv = *(const float4*)(&gamma[c]);
        float4 bv = *(const float4*)(&beta[c]);
        float4 o;
        o.x = (y[i][0] - mu) * rstd * gv.x + bv.x;
        o.y = (y[i][1] - mu) * rstd * gv.y + bv.y;
        o.z = (y[i][2] - mu) * rstd * gv.z + bv.z;
        o.w = (y[i][3] - mu) * rstd * gv.w + bv.w;
        *(float4*)(&orow[c]) = o;
    }
}

extern "C" void kernel_launch(void* const* d_in, const int* in_sizes, int n_in,
                              void* d_out, int out_size, void* d_ws, size_t ws_size,
                              hipStream_t stream)
{
    (void)in_sizes; (void)n_in; (void)out_size; (void)ws_size;
    const float* af    = (const float*)d_in[0];
    const float* Wq    = (const float*)d_in[1];
    const float* bq    = (const float*)d_in[2];
    const float* Wk    = (const float*)d_in[3];
    const float* bk    = (const float*)d_in[4];
    const float* Wv    = (const float*)d_in[5];
    const float* bv    = (const float*)d_in[6];
    const float* Wo    = (const float*)d_in[7];
    const float* bo    = (const float*)d_in[8];
    const float* gamma = (const float*)d_in[9];
    const float* beta  = (const float*)d_in[10];
    const int* a_sizes = (const int*)d_in[12];
    float* outp = (float*)d_out;

    // d_ws: qb, kb, vb (bf16 N x 768 each = 144 MiB; proven ws >= 192 MiB)
    bf16* qb = (bf16*)d_ws;
    bf16* kb = qb + (size_t)N_TOT * 768;
    bf16* vb = kb + (size_t)N_TOT * 768;          // ctx overwrites in place
    // d_out doubles as scratch until ln_kernel overwrites it (stream-ordered):
    // afb 50.3 MB + Wcat 3.4 MB + Wobf 1.1 MB < 100.6 MB output buffer
    bf16* afb  = (bf16*)d_out;
    bf16* Wcat = afb + (size_t)N_TOT * 768;
    bf16* Wobf = Wcat + (size_t)2304 * 768;

    cvt_all<<<dim3(12288 + 4*288), 256, 0, stream>>>(af, Wq, Wk, Wv, Wo, afb, Wcat, Wobf);
    gemm_qkv<<<dim3(1152), 512, 0, stream>>>(afb, Wcat, bq, bk, bv, qb, kb, vb);
    attn_kernel<<<dim3(M_MOL * NH_), 256, 0, stream>>>(qb, kb, vb, a_sizes);
    gemm_o<<<dim3(384), 512, 0, stream>>>(vb, Wobf, bo, qb);
    ln_kernel<<<dim3(N_TOT / 4), 256, 0, stream>>>(qb, af, gamma, beta, a_sizes, outp);
}